// Round 3
// baseline (207.151 us; speedup 1.0000x reference)
//
#include <hip/hip_runtime.h>

// SubjectConditionalLinear: y[b,n,o] = sum_h x[b,n,h] * W[sid[b],o,h] + bias[sid[b],o]
// x: [32,512,1024] f32, subject_id: [32] i32, weight: [8,1024,1024] f32, bias: [8,1024] f32
// out: [32,512,1024] f32
//
// R3: (1) cvt kernel: 16 elems/thread, unit-stride loads/stores, NT loads.
//     (2) GEMM: 32x32x16 MFMA (4060 FLOP/cyc vs 3378 for 16x16x32), same
//         m97-style staging: unpadded bf16 LDS tiles via global_load_lds x16.

constexpr int S_DIM = 8;
constexpr int O_DIM = 1024;
constexpr int H_DIM = 1024;
constexpr int B_DIM = 32;
constexpr int N_DIM = 512;

constexpr int BM = 128;
constexpr int BN = 128;
constexpr int BK = 64;
constexpr int NTHREADS = 256;

constexpr long long X_ELEMS = (long long)B_DIM * N_DIM * H_DIM;   // 16,777,216
constexpr long long W_ELEMS = (long long)S_DIM * O_DIM * H_DIM;   //  8,388,608
constexpr size_t XB_BYTES = (size_t)X_ELEMS * 2;                  // 32 MiB

typedef short bf16x8 __attribute__((ext_vector_type(8)));
typedef float f32x4 __attribute__((ext_vector_type(4)));
typedef float f32x2 __attribute__((ext_vector_type(2)));
typedef float f32x16 __attribute__((ext_vector_type(16)));
typedef __bf16 bf16x2 __attribute__((ext_vector_type(2)));

__device__ __forceinline__ unsigned int cvt_pk_bf16(float a, float b) {
  f32x2 v;
  v[0] = a;
  v[1] = b;
  bf16x2 r = __builtin_convertvector(v, bf16x2);  // v_cvt_pk_bf16_f32
  return __builtin_bit_cast(unsigned int, r);
}

__device__ __forceinline__ void gload_lds16(const void* g, void* l) {
  __builtin_amdgcn_global_load_lds(
      (const __attribute__((address_space(1))) unsigned int*)g,
      (__attribute__((address_space(3))) unsigned int*)l, 16, 0, 0);
}

// ---------- Phase 1: fp32 -> bf16 convert (x and all 8 weight matrices) ----
// Block-uniform split: blocks [0,4096) cover x, [4096,6144) cover weight.
// Per block: 4096 floats; chunk c: load float4 at c*1024 + tid*4 (unit-stride
// 16B/lane), store uint2 at same element offset (unit-stride 8B/lane).
__global__ __launch_bounds__(256) void cvt_kernel(
    const float* __restrict__ x, const float* __restrict__ w,
    unsigned short* __restrict__ xb, unsigned short* __restrict__ wb) {
  const int blk = blockIdx.x;
  const float* src;
  unsigned short* dst;
  long long base;
  if (blk < 4096) {
    src = x; dst = xb; base = (long long)blk * 4096;
  } else {
    src = w; dst = wb; base = (long long)(blk - 4096) * 4096;
  }
  const long long e0 = base + threadIdx.x * 4;
#pragma unroll
  for (int c = 0; c < 4; ++c) {
    const f32x4 v = __builtin_nontemporal_load((const f32x4*)(src + e0 + c * 1024));
    uint2 u;
    u.x = cvt_pk_bf16(v[0], v[1]);
    u.y = cvt_pk_bf16(v[2], v[3]);
    *(uint2*)(dst + e0 + c * 1024) = u;
  }
}

// ---------- Phase 2: bf16 MFMA GEMM, m97 staging + 32x32x16 compute --------
__global__ __launch_bounds__(NTHREADS, 4) void scl_gemm(
    const unsigned short* __restrict__ xb, const int* __restrict__ subject_id,
    const unsigned short* __restrict__ wb, const float* __restrict__ bias,
    float* __restrict__ out) {
  __shared__ __align__(16) unsigned short As[BM * BK];  // 16 KiB, unpadded
  __shared__ __align__(16) unsigned short Bs[BN * BK];  // 16 KiB, unpadded

  const int tid = threadIdx.x;
  const int b = blockIdx.z;
  const int n0 = blockIdx.x * BM;
  const int o0 = blockIdx.y * BN;
  const int sid = subject_id[b];

  const int lane = tid & 63;
  const int wid = tid >> 6;
  const int wm0 = (wid >> 1) * 64;  // wave 64x64 subtile
  const int wn0 = (wid & 1) * 64;
  const int lane32 = lane & 31;
  const int lhalf = lane >> 5;      // 0..1

  // Staging: wave w covers rows w*32..w*32+32 of each tile, 4 insts of 8 rows.
  const int srow = wid * 32 + (lane >> 3);
  const int skc = (lane & 7) * 8;
  const unsigned short* ag = xb + (size_t)(b * N_DIM + n0 + srow) * H_DIM + skc;
  const unsigned short* bg = wb + (size_t)(sid * O_DIM + o0 + srow) * H_DIM + skc;
  unsigned short* as_base = &As[(wid * 32) * BK];
  unsigned short* bs_base = &Bs[(wid * 32) * BK];

  f32x16 acc[2][2];
#pragma unroll
  for (int mi = 0; mi < 2; ++mi)
#pragma unroll
    for (int ni = 0; ni < 2; ++ni)
      acc[mi][ni] = (f32x16)(0.0f);

  for (int k0 = 0; k0 < H_DIM; k0 += BK) {
    __syncthreads();  // prior compute's ds_reads done before overwrite
#pragma unroll
    for (int i = 0; i < 4; ++i) {
      gload_lds16(ag + (size_t)(i * 8) * H_DIM + k0, as_base + i * 8 * BK);
      gload_lds16(bg + (size_t)(i * 8) * H_DIM + k0, bs_base + i * 8 * BK);
    }
    __syncthreads();  // drains vmcnt: LDS tiles complete

    // 32x32x16: A frag = 8 bf16/lane, m = lane&31, k = (lane>>5)*8 + j.
#pragma unroll
    for (int ks = 0; ks < BK; ks += 16) {
      const int kb = ks + lhalf * 8;
      bf16x8 af[2], bfr[2];
#pragma unroll
      for (int mi = 0; mi < 2; ++mi)
        af[mi] = *(const bf16x8*)(&As[(wm0 + mi * 32 + lane32) * BK + kb]);
#pragma unroll
      for (int ni = 0; ni < 2; ++ni)
        bfr[ni] = *(const bf16x8*)(&Bs[(wn0 + ni * 32 + lane32) * BK + kb]);
#pragma unroll
      for (int mi = 0; mi < 2; ++mi)
#pragma unroll
        for (int ni = 0; ni < 2; ++ni)
          acc[mi][ni] = __builtin_amdgcn_mfma_f32_32x32x16_bf16(
              af[mi], bfr[ni], acc[mi][ni], 0, 0, 0);
    }
  }

  // Epilogue. 32x32 C/D layout: col = lane&31, row = (reg&3)+8*(reg>>2)+4*(lane>>5).
  float bv[2];
#pragma unroll
  for (int ni = 0; ni < 2; ++ni)
    bv[ni] = bias[sid * O_DIM + o0 + wn0 + ni * 32 + lane32];

  float* outb = out + (size_t)(b * N_DIM + n0 + wm0) * O_DIM + o0 + wn0 + lane32;
#pragma unroll
  for (int mi = 0; mi < 2; ++mi) {
#pragma unroll
    for (int reg = 0; reg < 16; ++reg) {
      const int row = mi * 32 + (reg & 3) + 8 * (reg >> 2) + 4 * lhalf;
      float* orow = outb + (size_t)row * O_DIM;
#pragma unroll
      for (int ni = 0; ni < 2; ++ni)
        orow[ni * 32] = acc[mi][ni][reg] + bv[ni];
    }
  }
}

extern "C" void kernel_launch(void* const* d_in, const int* in_sizes, int n_in,
                              void* d_out, int out_size, void* d_ws, size_t ws_size,
                              hipStream_t stream) {
  const float* x = (const float*)d_in[0];
  const int* subject_id = (const int*)d_in[1];
  const float* weight = (const float*)d_in[2];
  const float* bias = (const float*)d_in[3];
  float* out = (float*)d_out;

  unsigned short* xb = (unsigned short*)d_ws;                       // 32 MiB
  unsigned short* wb = (unsigned short*)((char*)d_ws + XB_BYTES);   // 16 MiB

  cvt_kernel<<<6144, 256, 0, stream>>>(x, weight, xb, wb);

  dim3 grid(N_DIM / BM, O_DIM / BN, B_DIM);  // (4, 8, 32) = 1024 blocks
  scl_gemm<<<grid, NTHREADS, 0, stream>>>(xb, subject_id, wb, bias, out);
}

// Round 4
// 180.342 us; speedup vs baseline: 1.1487x; 1.1487x over previous
//
#include <hip/hip_runtime.h>

// SubjectConditionalLinear: y[b,n,o] = sum_h x[b,n,h] * W[sid[b],o,h] + bias[sid[b],o]
// x: [32,512,1024] f32, subject_id: [32] i32, weight: [8,1024,1024] f32, bias: [8,1024] f32
// out: [32,512,1024] f32
//
// R4: back to 16x16x32 MFMA (R3's 32x32 doubled bank conflicts -> -25us).
// NEW: XOR-swizzled LDS layout — row r's 16B k-chunk c stored at chunk c^(r&7).
// Implemented on the GLOBAL side of global_load_lds (LDS dest is lane-fixed);
// fragment ds_read_b128 then lands 2 lanes/bank (free) instead of 16-way.

constexpr int S_DIM = 8;
constexpr int O_DIM = 1024;
constexpr int H_DIM = 1024;
constexpr int B_DIM = 32;
constexpr int N_DIM = 512;

constexpr int BM = 128;
constexpr int BN = 128;
constexpr int BK = 64;
constexpr int NTHREADS = 256;

constexpr long long X_ELEMS = (long long)B_DIM * N_DIM * H_DIM;   // 16,777,216
constexpr long long W_ELEMS = (long long)S_DIM * O_DIM * H_DIM;   //  8,388,608
constexpr size_t XB_BYTES = (size_t)X_ELEMS * 2;                  // 32 MiB

typedef short bf16x8 __attribute__((ext_vector_type(8)));
typedef float f32x4 __attribute__((ext_vector_type(4)));
typedef float f32x2 __attribute__((ext_vector_type(2)));
typedef __bf16 bf16x2 __attribute__((ext_vector_type(2)));

__device__ __forceinline__ unsigned int cvt_pk_bf16(float a, float b) {
  f32x2 v;
  v[0] = a;
  v[1] = b;
  bf16x2 r = __builtin_convertvector(v, bf16x2);  // v_cvt_pk_bf16_f32
  return __builtin_bit_cast(unsigned int, r);
}

__device__ __forceinline__ void gload_lds16(const void* g, void* l) {
  __builtin_amdgcn_global_load_lds(
      (const __attribute__((address_space(1))) unsigned int*)g,
      (__attribute__((address_space(3))) unsigned int*)l, 16, 0, 0);
}

// ---------- Phase 1: fp32 -> bf16 convert (x and all 8 weight matrices) ----
__global__ __launch_bounds__(256) void cvt_kernel(
    const float* __restrict__ x, const float* __restrict__ w,
    unsigned short* __restrict__ xb, unsigned short* __restrict__ wb) {
  const int blk = blockIdx.x;
  const float* src;
  unsigned short* dst;
  long long base;
  if (blk < 4096) {
    src = x; dst = xb; base = (long long)blk * 4096;
  } else {
    src = w; dst = wb; base = (long long)(blk - 4096) * 4096;
  }
  const long long e0 = base + threadIdx.x * 4;
#pragma unroll
  for (int c = 0; c < 4; ++c) {
    const f32x4 v = __builtin_nontemporal_load((const f32x4*)(src + e0 + c * 1024));
    uint2 u;
    u.x = cvt_pk_bf16(v[0], v[1]);
    u.y = cvt_pk_bf16(v[2], v[3]);
    *(uint2*)(dst + e0 + c * 1024) = u;
  }
}

// ---------- Phase 2: bf16 MFMA GEMM, m97 staging + XOR swizzle -------------
__global__ __launch_bounds__(NTHREADS, 4) void scl_gemm(
    const unsigned short* __restrict__ xb, const int* __restrict__ subject_id,
    const unsigned short* __restrict__ wb, const float* __restrict__ bias,
    float* __restrict__ out) {
  __shared__ __align__(16) unsigned short As[BM * BK];  // 16 KiB
  __shared__ __align__(16) unsigned short Bs[BN * BK];  // 16 KiB

  const int tid = threadIdx.x;
  const int b = blockIdx.z;
  const int n0 = blockIdx.x * BM;
  const int o0 = blockIdx.y * BN;
  const int sid = subject_id[b];

  const int lane = tid & 63;
  const int wid = tid >> 6;
  const int wm0 = (wid >> 1) * 64;
  const int wn0 = (wid & 1) * 64;
  const int lcol = lane & 15;
  const int lq = lane >> 4;

  // Staging: wave w rows w*32..w*32+32, 4 insts of 8 rows each.
  // Lane L = rl*8 + pc: phys row rl = L>>3, phys chunk pc = L&7.
  // Swizzle: phys chunk pc holds logical chunk pc ^ (row&7); row&7 == rl
  // for every staging inst (row base is a multiple of 8).
  const int rl = lane >> 3;
  const int srow = wid * 32 + rl;
  const int skc = ((lane & 7) ^ rl) * 8;  // logical k-chunk this lane fetches
  const unsigned short* ag = xb + (size_t)(b * N_DIM + n0 + srow) * H_DIM + skc;
  const unsigned short* bg = wb + (size_t)(sid * O_DIM + o0 + srow) * H_DIM + skc;
  unsigned short* as_base = &As[(wid * 32) * BK];
  unsigned short* bs_base = &Bs[(wid * 32) * BK];

  f32x4 acc[4][4];
#pragma unroll
  for (int mi = 0; mi < 4; ++mi)
#pragma unroll
    for (int ni = 0; ni < 4; ++ni) {
      f32x4 z = {0.f, 0.f, 0.f, 0.f};
      acc[mi][ni] = z;
    }

  for (int k0 = 0; k0 < H_DIM; k0 += BK) {
    __syncthreads();
#pragma unroll
    for (int i = 0; i < 4; ++i) {
      gload_lds16(ag + (size_t)(i * 8) * H_DIM + k0, as_base + i * 8 * BK);
      gload_lds16(bg + (size_t)(i * 8) * H_DIM + k0, bs_base + i * 8 * BK);
    }
    __syncthreads();

#pragma unroll
    for (int kk = 0; kk < BK; kk += 32) {
      const int clog = (kk >> 3) + lq;  // logical 16B chunk index, 0..7
      bf16x8 af[4], bfr[4];
#pragma unroll
      for (int mi = 0; mi < 4; ++mi) {
        const int ar = wm0 + mi * 16 + lcol;
        af[mi] = *(const bf16x8*)(&As[ar * BK + ((clog ^ (ar & 7)) << 3)]);
      }
#pragma unroll
      for (int ni = 0; ni < 4; ++ni) {
        const int br = wn0 + ni * 16 + lcol;
        bfr[ni] = *(const bf16x8*)(&Bs[br * BK + ((clog ^ (br & 7)) << 3)]);
      }
#pragma unroll
      for (int mi = 0; mi < 4; ++mi)
#pragma unroll
        for (int ni = 0; ni < 4; ++ni)
          acc[mi][ni] = __builtin_amdgcn_mfma_f32_16x16x32_bf16(
              af[mi], bfr[ni], acc[mi][ni], 0, 0, 0);
    }
  }

  // Epilogue: C/D layout col = lane&15, row = (lane>>4)*4 + reg.
  float bv[4];
#pragma unroll
  for (int ni = 0; ni < 4; ++ni)
    bv[ni] = bias[sid * O_DIM + o0 + wn0 + ni * 16 + lcol];

  float* outb = out + (size_t)(b * N_DIM + n0 + wm0) * O_DIM + o0 + wn0 + lcol;
#pragma unroll
  for (int mi = 0; mi < 4; ++mi) {
#pragma unroll
    for (int r = 0; r < 4; ++r) {
      float* orow = outb + (size_t)(mi * 16 + lq * 4 + r) * O_DIM;
#pragma unroll
      for (int ni = 0; ni < 4; ++ni)
        orow[ni * 16] = acc[mi][ni][r] + bv[ni];
    }
  }
}

extern "C" void kernel_launch(void* const* d_in, const int* in_sizes, int n_in,
                              void* d_out, int out_size, void* d_ws, size_t ws_size,
                              hipStream_t stream) {
  const float* x = (const float*)d_in[0];
  const int* subject_id = (const int*)d_in[1];
  const float* weight = (const float*)d_in[2];
  const float* bias = (const float*)d_in[3];
  float* out = (float*)d_out;

  unsigned short* xb = (unsigned short*)d_ws;                       // 32 MiB
  unsigned short* wb = (unsigned short*)((char*)d_ws + XB_BYTES);   // 16 MiB

  cvt_kernel<<<6144, 256, 0, stream>>>(x, weight, xb, wb);

  dim3 grid(N_DIM / BM, O_DIM / BN, B_DIM);  // (4, 8, 32) = 1024 blocks
  scl_gemm<<<grid, NTHREADS, 0, stream>>>(xb, subject_id, wb, bias, out);
}